// Round 2
// baseline (439.007 us; speedup 1.0000x reference)
//
#include <hip/hip_runtime.h>

// CRY gate, DIM=2, N=24, C=0, T=1, J=1, K=2, B=2.
// d = g*2^23 + t*2^22 + s (big-endian digits), flat = d*2 + batch.
// Merged index i = 2s+batch in [0, 2^23): contiguous within each (g,t) quadrant.
// Quadrant strides (floats): t -> 2^23, g -> 2^24. Output real at 0, imag at 2^25.
// g=0: identity copy. g=1: [out_t0; out_t1] = [[c,-s],[-s,c]] [in_t0; in_t1],
// applied identically to real and imag parts (matrix is real).
//
// Pure streaming op (read-once/write-once, 512 MiB total) -> nontemporal
// loads/stores to skip L2 allocation.

typedef float f4 __attribute__((ext_vector_type(4)));

__global__ __launch_bounds__(256) void cry_kernel(
    const float* __restrict__ xr_, const float* __restrict__ xi_,
    const float* __restrict__ ang_, float* __restrict__ out_)
{
    const unsigned tid = blockIdx.x * 256u + threadIdx.x;   // [0, 2^21) float4 units

    float sv, cv;
    __sincosf(0.5f * ang_[0], &sv, &cv);

    const f4* xr  = (const f4*)xr_;
    const f4* xi  = (const f4*)xi_;
    f4*       out = (f4*)out_;

    const unsigned Q  = 1u << 21;  // target-bit stride, float4 units (2^23 floats / 4)
    const unsigned CS = 1u << 22;  // control-bit stride, float4 units (2^24 floats / 4)
    const unsigned IM = 1u << 23;  // imag-half offset in out, float4 units (2^25 floats / 4)

    // ---- control = 0: identity (pure copy) ----
    {
        f4 c0 = __builtin_nontemporal_load(xr + tid);
        f4 c1 = __builtin_nontemporal_load(xr + tid + Q);
        f4 c2 = __builtin_nontemporal_load(xi + tid);
        f4 c3 = __builtin_nontemporal_load(xi + tid + Q);
        __builtin_nontemporal_store(c0, out + tid);
        __builtin_nontemporal_store(c1, out + tid + Q);
        __builtin_nontemporal_store(c2, out + IM + tid);
        __builtin_nontemporal_store(c3, out + IM + tid + Q);
    }

    // ---- control = 1: rotate target (levels 0,1) by theta/2 ----
    {
        // real part
        f4 a = __builtin_nontemporal_load(xr + CS + tid);
        f4 b = __builtin_nontemporal_load(xr + CS + tid + Q);
        f4 r0 = cv * a - sv * b;
        f4 r1 = cv * b - sv * a;
        __builtin_nontemporal_store(r0, out + CS + tid);
        __builtin_nontemporal_store(r1, out + CS + tid + Q);

        // imag part
        a = __builtin_nontemporal_load(xi + CS + tid);
        b = __builtin_nontemporal_load(xi + CS + tid + Q);
        r0 = cv * a - sv * b;
        r1 = cv * b - sv * a;
        __builtin_nontemporal_store(r0, out + IM + CS + tid);
        __builtin_nontemporal_store(r1, out + IM + CS + tid + Q);
    }
}

extern "C" void kernel_launch(void* const* d_in, const int* in_sizes, int n_in,
                              void* d_out, int out_size, void* d_ws, size_t ws_size,
                              hipStream_t stream) {
    const float* xr  = (const float*)d_in[0];
    const float* xi  = (const float*)d_in[1];
    const float* ang = (const float*)d_in[2];
    float* out = (float*)d_out;

    // 2^21 threads, each handling one float4 per (g,t,part) octant
    const int threads = 256;
    const int blocks  = (1u << 21) / threads;  // 8192
    cry_kernel<<<blocks, threads, 0, stream>>>(xr, xi, ang, out);
}